// Round 4
// baseline (274.797 us; speedup 1.0000x reference)
//
#include <hip/hip_runtime.h>

// Problem constants (B=4, N=1024, DIM=1024, H=16, DH=64)
// Dtype model (r5-proven): tensor inputs fp32, masks int32, d_out fp32.
#define NTOK 4096
#define AST 72   // attn LDS row stride in halves (144 B: 16B-aligned, bank-stride 4)

typedef _Float16 half4v __attribute__((ext_vector_type(4)));
typedef _Float16 half8 __attribute__((ext_vector_type(8)));
typedef float floatx4 __attribute__((ext_vector_type(4)));

__device__ __forceinline__ half8 cvt8(float4 a, float4 b) {
  half8 h;
  h[0] = (_Float16)a.x; h[1] = (_Float16)a.y; h[2] = (_Float16)a.z; h[3] = (_Float16)a.w;
  h[4] = (_Float16)b.x; h[5] = (_Float16)b.y; h[6] = (_Float16)b.z; h[7] = (_Float16)b.w;
  return h;
}

#if defined(__has_builtin)
#if __has_builtin(__builtin_amdgcn_global_load_lds)
#define HAS_GLL 1
#endif
#endif

#ifdef HAS_GLL
#define STAGE16(gp, lp)                                                        \
  __builtin_amdgcn_global_load_lds(                                           \
      (const __attribute__((address_space(1))) void*)(gp),                     \
      (__attribute__((address_space(3))) void*)(lp), 16, 0, 0)
#else
#define STAGE16(gp, lp)                                                        \
  do { *(half8*)((_Float16*)(lp) + lane * 8) = *(const half8*)(gp); } while (0)
#endif

// ---------------------------------------------------------------------------
// Mask canonicalization (r3 proved masks arrive int32; kept for robustness).
// ---------------------------------------------------------------------------
__device__ __forceinline__ int mask_is_bytes(const int* p) {
  int bad = 0;
#pragma unroll
  for (int i = 0; i < 64; i++) bad |= (((unsigned int)p[i]) > 1u);
  return bad;
}

// ---------------------------------------------------------------------------
// One-shot fp32 -> f16 conversion of GEMM operands (Q,K,V inputs + 4 weights)
// + mask canonicalization fused into the same launch (blocks >= 8192).
// ---------------------------------------------------------------------------
__global__ __launch_bounds__(256) void cvt_all(
    const float* __restrict__ Q, const float* __restrict__ K, const float* __restrict__ V,
    const float* __restrict__ Wq, const float* __restrict__ Wk, const float* __restrict__ Wv,
    const float* __restrict__ Wo,
    const int* __restrict__ srcQ, const int* __restrict__ srcK,
    _Float16* __restrict__ Xq, _Float16* __restrict__ Xk, _Float16* __restrict__ Xv,
    _Float16* __restrict__ Wqh, _Float16* __restrict__ Wkh, _Float16* __restrict__ Wvh,
    _Float16* __restrict__ Woh,
    int* __restrict__ dstQ, int* __restrict__ dstK)
{
  const int blk = blockIdx.x;
  if (blk >= 8192) {  // fused mask_prep: 16 blocks x 256 = 4096 tokens
    const int t = (blk - 8192) * 256 + threadIdx.x;
    const int bq = mask_is_bytes(srcQ);
    const int bk = mask_is_bytes(srcK);
    dstQ[t] = bq ? (int)((const unsigned char*)srcQ)[t] : srcQ[t];
    dstK[t] = bk ? (int)((const unsigned char*)srcK)[t] : srcK[t];
    return;
  }
  const float* src; _Float16* dst; size_t off;
  if      (blk < 2048) { src = Q;  dst = Xq;  off = (size_t)blk * 2048; }
  else if (blk < 4096) { src = K;  dst = Xk;  off = (size_t)(blk - 2048) * 2048; }
  else if (blk < 6144) { src = V;  dst = Xv;  off = (size_t)(blk - 4096) * 2048; }
  else if (blk < 6656) { src = Wq; dst = Wqh; off = (size_t)(blk - 6144) * 2048; }
  else if (blk < 7168) { src = Wk; dst = Wkh; off = (size_t)(blk - 6656) * 2048; }
  else if (blk < 7680) { src = Wv; dst = Wvh; off = (size_t)(blk - 7168) * 2048; }
  else                 { src = Wo; dst = Woh; off = (size_t)(blk - 7680) * 2048; }
  const size_t i = off + (size_t)threadIdx.x * 8;
  const float4 a = *(const float4*)(src + i);
  const float4 b = *(const float4*)(src + i + 4);
  *(half8*)(dst + i) = cvt8(a, b);
}

// ---------------------------------------------------------------------------
// 128x128 f16 GEMM core, 2-phase double-buffered (T3-min recipe):
//   prologue STAGE(buf0); barrier; loop { STAGE(buf^1, kt+1); compute(buf);
//   barrier; }  -> ONE barrier per K-step, next-tile global_load_lds overlaps
//   the ds_read+MFMA of the current tile.
// ---------------------------------------------------------------------------
#define GEMM97_CORE(AH, BH)                                                    \
  __shared__ _Float16 sA[2][128 * 32];                                         \
  __shared__ _Float16 sB[2][128 * 32];                                         \
  const int t = threadIdx.x;                                                   \
  const int bn = blockIdx.y, bm = blockIdx.x;                                  \
  const int lane = t & 63, wv = t >> 6, quad = lane >> 4, l16 = lane & 15;     \
  const int wm = wv & 1, wn = wv >> 1;                                         \
  const int srow = wv * 32 + (lane >> 2);                                      \
  const int scol = (lane & 3) * 8;                                             \
  floatx4 acc[4][4] = {};                                                      \
  const _Float16* gA = AH + (size_t)(bm * 128 + srow) * 1024 + scol;           \
  const _Float16* gB = BH + (size_t)(bn * 128 + srow) * 1024 + scol;           \
  STAGE16(gA,         &sA[0][(wv * 32) * 32]);                                 \
  STAGE16(gA + 16384, &sA[0][(wv * 32 + 16) * 32]);                            \
  STAGE16(gB,         &sB[0][(wv * 32) * 32]);                                 \
  STAGE16(gB + 16384, &sB[0][(wv * 32 + 16) * 32]);                            \
  __syncthreads();                                                             \
  for (int kt = 0; kt < 32; kt++) {                                            \
    const int cur = kt & 1;                                                    \
    if (kt < 31) {                                                             \
      STAGE16(gA + (kt + 1) * 32,         &sA[cur ^ 1][(wv * 32) * 32]);       \
      STAGE16(gA + (kt + 1) * 32 + 16384, &sA[cur ^ 1][(wv * 32 + 16) * 32]);  \
      STAGE16(gB + (kt + 1) * 32,         &sB[cur ^ 1][(wv * 32) * 32]);       \
      STAGE16(gB + (kt + 1) * 32 + 16384, &sB[cur ^ 1][(wv * 32 + 16) * 32]);  \
    }                                                                          \
    half8 af[4], bf[4];                                                        \
    _Pragma("unroll")                                                          \
    for (int s = 0; s < 4; s++)                                                \
      af[s] = *(const half8*)&sA[cur][(wm * 64 + s * 16 + l16) * 32 + quad * 8]; \
    _Pragma("unroll")                                                          \
    for (int u = 0; u < 4; u++)                                                \
      bf[u] = *(const half8*)&sB[cur][(wn * 64 + u * 16 + l16) * 32 + quad * 8]; \
    _Pragma("unroll")                                                          \
    for (int s = 0; s < 4; s++)                                                \
      _Pragma("unroll")                                                        \
      for (int u = 0; u < 4; u++)                                              \
        acc[s][u] = __builtin_amdgcn_mfma_f32_16x16x32_f16(af[s], bf[u],       \
                                                           acc[s][u], 0, 0, 0); \
    __syncthreads();                                                           \
  }

// ---------------------------------------------------------------------------
// Batched QKV projection: blockIdx.z selects (A, W, mask, out). All f16 out.
// z==2 (V): epilogue writes TRANSPOSED Vt[(b*16+h)*64+d][k] via per-wave LDS
// transpose (each wave's 64x64 sub-tile = one head x 64 tokens; no barrier,
// no extra HBM round-trip -> v_transpose kernel eliminated).
// V-mask is skipped: masked-k columns get P=exp(-1e30)=0 exactly in attn,
// so unmasked (finite) V values there contribute 0, matching the reference.
// ---------------------------------------------------------------------------
__global__ __launch_bounds__(256) void qkv_gemm(
    const _Float16* __restrict__ Xq, const _Float16* __restrict__ Xk,
    const _Float16* __restrict__ Xv,
    const _Float16* __restrict__ Wqh, const _Float16* __restrict__ Wkh,
    const _Float16* __restrict__ Wvh,
    const int* __restrict__ mQ, const int* __restrict__ mK,
    _Float16* __restrict__ Qh, _Float16* __restrict__ Kh, _Float16* __restrict__ Vt)
{
  const int z = blockIdx.z;
  const _Float16* AH = (z == 0) ? Xq : (z == 1) ? Xk : Xv;
  const _Float16* BH = (z == 0) ? Wqh : (z == 1) ? Wkh : Wvh;
  GEMM97_CORE(AH, BH)
  if (z < 2) {
    const int* msk = (z == 0) ? mQ : mK;
    _Float16* out = (z == 0) ? Qh : Kh;
#pragma unroll
    for (int s = 0; s < 4; s++)
#pragma unroll
      for (int rr = 0; rr < 4; rr++) {
        const int row = bm * 128 + wm * 64 + s * 16 + quad * 4 + rr;
        const int m = msk[row];
#pragma unroll
        for (int u = 0; u < 4; u++)
          out[(size_t)row * 1024 + bn * 128 + wn * 64 + u * 16 + l16] =
              m ? (_Float16)0.0f : (_Float16)acc[s][u][rr];
      }
  } else {
    // per-wave 64x64 transpose through private LDS scratch (stride 36 halves)
    _Float16* scr = (wv == 0) ? &sA[0][0] : (wv == 1) ? &sA[1][0]
                  : (wv == 2) ? &sB[0][0] : &sB[1][0];
    const int h = 2 * bn + wn;                 // head owned by this wave
    const int krow0 = bm * 128 + wm * 64;      // global token base (64 rows)
    const int bq = krow0 >> 10;                // batch
    const int kloc = krow0 & 1023;             // token offset within batch
    const int dl = lane & 31, kh = lane >> 5;
#pragma unroll
    for (int p = 0; p < 2; p++) {              // two 32-dim column halves
#pragma unroll
      for (int up = 0; up < 2; up++) {
        const int u = p * 2 + up;
#pragma unroll
        for (int s = 0; s < 4; s++)
#pragma unroll
          for (int rr = 0; rr < 4; rr++)
            scr[(s * 16 + quad * 4 + rr) * 36 + up * 16 + l16] =
                (_Float16)acc[s][u][rr];
      }
      // same-wave read-back (compiler orders via lgkmcnt); transposed out
      half8 o[4];
#pragma unroll
      for (int j = 0; j < 32; j++)
        ((_Float16*)o)[j] = scr[(kh * 32 + j) * 36 + dl];
      _Float16* dst = Vt + ((size_t)((bq * 16 + h) * 64 + p * 32 + dl)) * 1024
                         + kloc + kh * 32;
      *(half8*)dst = o[0]; *(half8*)(dst + 8) = o[1];
      *(half8*)(dst + 16) = o[2]; *(half8*)(dst + 24) = o[3];
    }
  }
}

// ---------------------------------------------------------------------------
// 128x128 f16 GEMM (Wo), 2-phase core (was 128x64: 2x MFMA density/wave).
// Epilogue: O2 = X1 + gelu_exact(X1 @ Wo^T). Grid (32,8) = 256 blocks.
// ---------------------------------------------------------------------------
__global__ __launch_bounds__(256) void gemm_wo(
    const _Float16* __restrict__ AH, const _Float16* __restrict__ BH,
    const float* __restrict__ X1, float* __restrict__ O2)
{
  GEMM97_CORE(AH, BH)
#pragma unroll
  for (int s = 0; s < 4; s++)
#pragma unroll
    for (int rr = 0; rr < 4; rr++) {
      const int row = bm * 128 + wm * 64 + s * 16 + quad * 4 + rr;
#pragma unroll
      for (int u = 0; u < 4; u++) {
        const size_t idx = (size_t)row * 1024 + bn * 128 + wn * 64 + u * 16 + l16;
        const float hv = acc[s][u][rr];
        const float ge = 0.5f * hv * (1.0f + erff(hv * 0.70710678118654752f));
        O2[idx] = X1[idx] + ge;   // masked rows: X1=0 -> 0 (matches ref)
      }
    }
}

// ---------------------------------------------------------------------------
// MFMA flash attention v4 (r1-proven 45.6us version):
//   - no-max softmax: p = expf(s*scale + bias); bias=-1e30 underflows to 0.
//   - T14 reg prefetch of next K/V tile right after the second barrier.
//   - T5 setprio around both MFMA clusters.
// ---------------------------------------------------------------------------
__global__ __launch_bounds__(256) void attn_mfma3(
    const _Float16* __restrict__ Qh, const _Float16* __restrict__ Kh,
    const _Float16* __restrict__ Vt, const int* __restrict__ maskQ,
    const int* __restrict__ maskK, float* __restrict__ O1)
{
  __shared__ _Float16 sK[64 * AST];
  __shared__ _Float16 sV[64 * AST];
  __shared__ _Float16 sQP[64 * AST];   // Q tile at start; per-wave P rows in loop
  __shared__ float bias[1024];

  const int t = threadIdx.x;
  const int qt = blockIdx.x, bh = blockIdx.y;
  const int b = bh >> 4, h = bh & 15;
  const int q0 = qt * 64;
  const size_t base = (size_t)b * 1024;
  const int wv = t >> 6, lane = t & 63, quad = lane >> 4, l16 = lane & 15;
  const int r = t >> 2, c0 = (t & 3) * 16;

  // prologue: issue K/V tile-0 loads first (latency hides under bias+Q stage)
  const _Float16* kbase = Kh + (base + r) * 1024 + h * 64 + c0;
  const _Float16* vbase = Vt + ((size_t)bh * 64 + r) * 1024 + c0;
  half8 k0v = *(const half8*)kbase;
  half8 k1v = *(const half8*)(kbase + 8);
  half8 v0v = *(const half8*)vbase;
  half8 v1v = *(const half8*)(vbase + 8);

  for (int i = t; i < 1024; i += 256)
    bias[i] = maskK[b * 1024 + i] ? -1e30f : 0.0f;

  {  // stage Q tile (pure f16 copy)
    const _Float16* qp = Qh + (base + q0 + r) * 1024 + h * 64 + c0;
    *(half8*)&sQP[r * AST + c0] = *(const half8*)qp;
    *(half8*)&sQP[r * AST + c0 + 8] = *(const half8*)(qp + 8);
  }
  __syncthreads();

  // Q B-operand frags (wave's 16 q = wv*16 + l16), held in regs for whole loop
  const half8 bq0 = *(const half8*)&sQP[(wv * 16 + l16) * AST + quad * 8];
  const half8 bq1 = *(const half8*)&sQP[(wv * 16 + l16) * AST + 32 + quad * 8];

  float l_i = 0.0f;                    // per-lane: column q = wv*16 + l16
  floatx4 acc_o[4] = {};               // O C-layout: row q=quad*4+rr, col d=nt*16+l16

  for (int kt = 0; kt < 16; kt++) {
    __syncthreads();
    *(half8*)&sK[r * AST + c0]     = k0v;
    *(half8*)&sK[r * AST + c0 + 8] = k1v;
    *(half8*)&sV[r * AST + c0]     = v0v;
    *(half8*)&sV[r * AST + c0 + 8] = v1v;
    __syncthreads();

    // T14: prefetch next K/V tile into regs; latency hidden by compute below
    if (kt < 15) {
      const _Float16* kp = kbase + (size_t)(kt + 1) * 64 * 1024;
      const _Float16* vp = vbase + (kt + 1) * 64;
      k0v = *(const half8*)kp;
      k1v = *(const half8*)(kp + 8);
      v0v = *(const half8*)vp;
      v1v = *(const half8*)(vp + 8);
    }

    // S^T[k][q]: A = K rows, B = Q rows. s[mt][rr]: k = mt*16+quad*4+rr, q = wv*16+l16
    floatx4 s[4] = {};
    __builtin_amdgcn_s_setprio(1);
#pragma unroll
    for (int mt = 0; mt < 4; mt++) {
      const half8 ak0 = *(const half8*)&sK[(mt * 16 + l16) * AST + quad * 8];
      const half8 ak1 = *(const half8*)&sK[(mt * 16 + l16) * AST + 32 + quad * 8];
      s[mt] = __builtin_amdgcn_mfma_f32_16x16x32_f16(ak0, bq0, s[mt], 0, 0, 0);
      s[mt] = __builtin_amdgcn_mfma_f32_16x16x32_f16(ak1, bq1, s[mt], 0, 0, 0);
    }
    __builtin_amdgcn_s_setprio(0);

    // exact softmax numerator, no max-subtraction (scores bounded << 88):
    // masked k: bias=-1e30 -> expf underflows to exactly 0.
    float rsum = 0.0f;
#pragma unroll
    for (int mt = 0; mt < 4; mt++) {
      const float4 b4 = *(const float4*)&bias[kt * 64 + mt * 16 + quad * 4];
      const float p0 = __expf(s[mt][0] * 0.03125f + b4.x);
      const float p1 = __expf(s[mt][1] * 0.03125f + b4.y);
      const float p2 = __expf(s[mt][2] * 0.03125f + b4.z);
      const float p3 = __expf(s[mt][3] * 0.03125f + b4.w);
      s[mt][0] = p0; s[mt][1] = p1; s[mt][2] = p2; s[mt][3] = p3;
      rsum += (p0 + p1) + (p2 + p3);
    }
    rsum += __shfl_xor(rsum, 16);
    rsum += __shfl_xor(rsum, 32);
    l_i += rsum;

    // P^T -> wave-private LDS rows q, packed half4 along k (4x b64 writes)
#pragma unroll
    for (int mt = 0; mt < 4; mt++) {
      half4v pv;
      pv[0] = (_Float16)s[mt][0]; pv[1] = (_Float16)s[mt][1];
      pv[2] = (_Float16)s[mt][2]; pv[3] = (_Float16)s[mt][3];
      *(half4v*)&sQP[(wv * 16 + l16) * AST + mt * 16 + quad * 4] = pv;
    }

    // PV: A = P rows q, B = V^T rows d
    const half8 ap0 = *(const half8*)&sQP[(wv * 16 + l16) * AST + quad * 8];
    const half8 ap1 = *(const half8*)&sQP[(wv * 16 + l16) * AST + 32 + quad * 8];
    __builtin_amdgcn_s_setprio(1);
#pragma unroll
    for (int nt = 0; nt < 4; nt++) {
      const half8 bv0 = *(const half8*)&sV[(nt * 16 + l16) * AST + quad * 8];
      const half8 bv1 = *(const half8*)&sV[(nt * 16 + l16) * AST + 32 + quad * 8];
      acc_o[nt] = __builtin_amdgcn_mfma_f32_16x16x32_f16(ap0, bv0, acc_o[nt], 0, 0, 0);
      acc_o[nt] = __builtin_amdgcn_mfma_f32_16x16x32_f16(ap1, bv1, acc_o[nt], 0, 0, 0);
    }
    __builtin_amdgcn_s_setprio(0);
  }

  // epilogue: O1 = maskQ ? 0 : Qh + O/l   (l broadcast column->row)
  float il[4];
#pragma unroll
  for (int rr = 0; rr < 4; rr++) {
    const float lq = __shfl(l_i, quad * 4 + rr);
    il[rr] = (lq > 0.0f) ? 1.0f / lq : 0.0f;
  }
#pragma unroll
  for (int rr = 0; rr < 4; rr++) {
    const int row = q0 + wv * 16 + quad * 4 + rr;
    const int mq = maskQ[b * 1024 + row];
#pragma unroll
    for (int nt = 0; nt < 4; nt++) {
      const size_t gi = (base + row) * 1024 + h * 64 + nt * 16 + l16;
      O1[gi] = mq ? 0.0f : ((float)Qh[gi] + acc_o[nt][rr] * il[rr]);
    }
  }
}

// ---------------------------------------------------------------------------
// LayerNorm (one row of 1024 per block), fp32 in; fp32 out (+ optional f16).
// ---------------------------------------------------------------------------
__device__ __forceinline__ void ln_stats(float4 x, int t, float* mean, float* rinv) {
  float s = x.x + x.y + x.z + x.w;
  float s2 = x.x * x.x + x.y * x.y + x.z * x.z + x.w * x.w;
#pragma unroll
  for (int off = 32; off >= 1; off >>= 1) { s += __shfl_xor(s, off); s2 += __shfl_xor(s2, off); }
  __shared__ float red[8];
  __shared__ float sm[2];
  const int wv = t >> 6, lane = t & 63;
  if (lane == 0) { red[wv] = s; red[4 + wv] = s2; }
  __syncthreads();
  if (t == 0) {
    const float S = red[0] + red[1] + red[2] + red[3];
    const float S2 = red[4] + red[5] + red[6] + red[7];
    const float m = S * (1.0f / 1024.0f);
    const float v = S2 * (1.0f / 1024.0f) - m * m;
    sm[0] = m; sm[1] = rsqrtf(v + 1e-5f);
  }
  __syncthreads();
  *mean = sm[0]; *rinv = sm[1];
}

__global__ __launch_bounds__(256) void ln_f32(
    const float* __restrict__ X, const float* __restrict__ g,
    const float* __restrict__ bta, const int* __restrict__ mask,
    float* __restrict__ out)
{
  const int rr = blockIdx.x, t = threadIdx.x, c = 4 * t;
  const float4 x = *(const float4*)&X[(size_t)rr * 1024 + c];
  float mean, ri;
  ln_stats(x, t, &mean, &ri);
  const int msk = mask[rr];
  const float4 gg = *(const float4*)&g[c];
  const float4 bb = *(const float4*)&bta[c];
  float4 o;
  o.x = msk ? 0.f : (x.x - mean) * ri * gg.x + bb.x;
  o.y = msk ? 0.f : (x.y - mean) * ri * gg.y + bb.y;
  o.z = msk ? 0.f : (x.z - mean) * ri * gg.z + bb.z;
  o.w = msk ? 0.f : (x.w - mean) * ri * gg.w + bb.w;
  *(float4*)&out[(size_t)rr * 1024 + c] = o;
}

__global__ __launch_bounds__(256) void ln_f32h(
    const float* __restrict__ X, const float* __restrict__ g,
    const float* __restrict__ bta, const int* __restrict__ mask,
    float* __restrict__ out, _Float16* __restrict__ outh)
{
  const int rr = blockIdx.x, t = threadIdx.x, c = 4 * t;
  const float4 x = *(const float4*)&X[(size_t)rr * 1024 + c];
  float mean, ri;
  ln_stats(x, t, &mean, &ri);
  const int msk = mask[rr];
  const float4 gg = *(const float4*)&g[c];
  const float4 bb = *(const float4*)&bta[c];
  float4 o;
  o.x = msk ? 0.f : (x.x - mean) * ri * gg.x + bb.x;
  o.y = msk ? 0.f : (x.y - mean) * ri * gg.y + bb.y;
  o.z = msk ? 0.f : (x.z - mean) * ri * gg.z + bb.z;
  o.w = msk ? 0.f : (x.w - mean) * ri * gg.w + bb.w;
  const size_t idx = (size_t)rr * 1024 + c;
  *(float4*)&out[idx] = o;
  half4v hh;
  hh[0] = (_Float16)o.x; hh[1] = (_Float16)o.y;
  hh[2] = (_Float16)o.z; hh[3] = (_Float16)o.w;
  *(half4v*)&outh[idx] = hh;
}

// ---------------------------------------------------------------------------
extern "C" void kernel_launch(void* const* d_in, const int* in_sizes, int n_in,
                              void* d_out, int out_size, void* d_ws, size_t ws_size,
                              hipStream_t stream)
{
  const float* Q  = (const float*)d_in[0];
  const float* K  = (const float*)d_in[1];
  const float* V  = (const float*)d_in[2];
  const float* Wq = (const float*)d_in[3];
  const float* Wk = (const float*)d_in[4];
  const float* Wv = (const float*)d_in[5];
  const float* Wo = (const float*)d_in[6];
  const float* g1 = (const float*)d_in[7];
  const float* b1 = (const float*)d_in[8];
  const float* g2 = (const float*)d_in[9];
  const float* b2 = (const float*)d_in[10];
  float* out = (float*)d_out;

  char* base = (char*)d_ws;
  const size_t MB_ = 1024 * 1024;
  _Float16* Xq  = (_Float16*)(base +  0 * MB_);   // [0,8)
  _Float16* Xk  = (_Float16*)(base +  8 * MB_);   // [8,16)
  _Float16* Xv  = (_Float16*)(base + 16 * MB_);   // [16,24)
  _Float16* Wqh = (_Float16*)(base + 24 * MB_);   // [24,26)
  _Float16* Wkh = (_Float16*)(base + 26 * MB_);   // [26,28)
  _Float16* Wvh = (_Float16*)(base + 28 * MB_);   // [28,30)
  _Float16* Woh = (_Float16*)(base + 30 * MB_);   // [30,32)
  _Float16* Qh  = (_Float16*)(base + 32 * MB_);   // [32,40)
  _Float16* Kh  = (_Float16*)(base + 40 * MB_);   // [40,48)
  _Float16* Vt  = (_Float16*)(base + 56 * MB_);   // [56,64)  (Vh slot [48,56) now unused)
  float*    O1  = (float*)(base + 64 * MB_);      // [64,80)
  int*      mQ  = (int*)(base + 80 * MB_);
  int*      mK  = mQ + NTOK;                      // peak: 80 MB + 32 KB (r8-proven)
  // post-attention aliases (source regions dead):
  float*    X1  = (float*)(base + 0 * MB_);       // over Xq∪Xk
  _Float16* X1h = (_Float16*)(base + 16 * MB_);   // over Xv
  float*    O2  = (float*)(base + 32 * MB_);      // over Qh∪Kh

  const dim3 bb(256);
  cvt_all<<<dim3(8208), bb, 0, stream>>>(Q, K, V, Wq, Wk, Wv, Wo,
                                         (const int*)d_in[11], (const int*)d_in[12],
                                         Xq, Xk, Xv, Wqh, Wkh, Wvh, Woh, mQ, mK);
  qkv_gemm<<<dim3(32, 8, 3), bb, 0, stream>>>(Xq, Xk, Xv, Wqh, Wkh, Wvh,
                                              mQ, mK, Qh, Kh, Vt);
  attn_mfma3<<<dim3(16, 64), bb, 0, stream>>>(Qh, Kh, Vt, mQ, mK, O1);
  ln_f32h<<<dim3(4096), bb, 0, stream>>>(O1, g1, b1, mQ, X1, X1h);
  gemm_wo<<<dim3(32, 8), bb, 0, stream>>>(X1h, Woh, X1, O2);
  ln_f32<<<dim3(4096), bb, 0, stream>>>(O2, g2, b2, mQ, out);
}

// Round 5
// 250.316 us; speedup vs baseline: 1.0978x; 1.0978x over previous
//
#include <hip/hip_runtime.h>

// Problem constants (B=4, N=1024, DIM=1024, H=16, DH=64)
// Dtype model (r5-proven): tensor inputs fp32, masks int32, d_out fp32.
#define NTOK 4096
#define AST 72   // attn LDS row stride in halves (144 B: 16B-aligned, bank-stride 4)

typedef _Float16 half4v __attribute__((ext_vector_type(4)));
typedef _Float16 half8 __attribute__((ext_vector_type(8)));
typedef float floatx4 __attribute__((ext_vector_type(4)));

__device__ __forceinline__ half8 cvt8(float4 a, float4 b) {
  half8 h;
  h[0] = (_Float16)a.x; h[1] = (_Float16)a.y; h[2] = (_Float16)a.z; h[3] = (_Float16)a.w;
  h[4] = (_Float16)b.x; h[5] = (_Float16)b.y; h[6] = (_Float16)b.z; h[7] = (_Float16)b.w;
  return h;
}

#if defined(__has_builtin)
#if __has_builtin(__builtin_amdgcn_global_load_lds)
#define HAS_GLL 1
#endif
#endif

#ifdef HAS_GLL
#define STAGE16(gp, lp)                                                        \
  __builtin_amdgcn_global_load_lds(                                           \
      (const __attribute__((address_space(1))) void*)(gp),                     \
      (__attribute__((address_space(3))) void*)(lp), 16, 0, 0)
#else
#define STAGE16(gp, lp)                                                        \
  do { *(half8*)((_Float16*)(lp) + lane * 8) = *(const half8*)(gp); } while (0)
#endif

// ---------------------------------------------------------------------------
// Mask canonicalization (r3 proved masks arrive int32; kept for robustness).
// ---------------------------------------------------------------------------
__device__ __forceinline__ int mask_is_bytes(const int* p) {
  int bad = 0;
#pragma unroll
  for (int i = 0; i < 64; i++) bad |= (((unsigned int)p[i]) > 1u);
  return bad;
}

// ---------------------------------------------------------------------------
// One-shot fp32 -> f16 conversion of GEMM operands (Q,K,V inputs + 4 weights)
// + mask canonicalization fused into the same launch (blocks >= 8192).
// ---------------------------------------------------------------------------
__global__ __launch_bounds__(256) void cvt_all(
    const float* __restrict__ Q, const float* __restrict__ K, const float* __restrict__ V,
    const float* __restrict__ Wq, const float* __restrict__ Wk, const float* __restrict__ Wv,
    const float* __restrict__ Wo,
    const int* __restrict__ srcQ, const int* __restrict__ srcK,
    _Float16* __restrict__ Xq, _Float16* __restrict__ Xk, _Float16* __restrict__ Xv,
    _Float16* __restrict__ Wqh, _Float16* __restrict__ Wkh, _Float16* __restrict__ Wvh,
    _Float16* __restrict__ Woh,
    int* __restrict__ dstQ, int* __restrict__ dstK)
{
  const int blk = blockIdx.x;
  if (blk >= 8192) {  // fused mask_prep: 16 blocks x 256 = 4096 tokens
    const int t = (blk - 8192) * 256 + threadIdx.x;
    const int bq = mask_is_bytes(srcQ);
    const int bk = mask_is_bytes(srcK);
    dstQ[t] = bq ? (int)((const unsigned char*)srcQ)[t] : srcQ[t];
    dstK[t] = bk ? (int)((const unsigned char*)srcK)[t] : srcK[t];
    return;
  }
  const float* src; _Float16* dst; size_t off;
  if      (blk < 2048) { src = Q;  dst = Xq;  off = (size_t)blk * 2048; }
  else if (blk < 4096) { src = K;  dst = Xk;  off = (size_t)(blk - 2048) * 2048; }
  else if (blk < 6144) { src = V;  dst = Xv;  off = (size_t)(blk - 4096) * 2048; }
  else if (blk < 6656) { src = Wq; dst = Wqh; off = (size_t)(blk - 6144) * 2048; }
  else if (blk < 7168) { src = Wk; dst = Wkh; off = (size_t)(blk - 6656) * 2048; }
  else if (blk < 7680) { src = Wv; dst = Wvh; off = (size_t)(blk - 7168) * 2048; }
  else                 { src = Wo; dst = Woh; off = (size_t)(blk - 7680) * 2048; }
  const size_t i = off + (size_t)threadIdx.x * 8;
  const float4 a = *(const float4*)(src + i);
  const float4 b = *(const float4*)(src + i + 4);
  *(half8*)(dst + i) = cvt8(a, b);
}

// ---------------------------------------------------------------------------
// 128x128 f16 GEMM core, 2-phase double-buffered (T3-min recipe), ONE barrier
// per K-step. Chunk-XOR LDS swizzle (rule #21: linear gload_lds dest +
// inverse-permuted per-lane SOURCE + XOR'd read chunk). Both sides fold into
// loop-invariant lane constants -> zero runtime cost; ds_read_b128 bank
// aliasing 8-way -> 4-way.
//   stage:  lane l writes LDS chunk (row=l>>2, c=l&3); it loads global chunk
//           (row, (l&3) ^ ((l>>2)&3))  [row&3 == (l>>2)&3]
//   read:   global chunk q of row lives at LDS chunk q ^ (row&3) = q ^ (l16&3)
// ---------------------------------------------------------------------------
#define GEMM97_CORE(AH, BH)                                                    \
  __shared__ _Float16 sA[2][128 * 32];                                         \
  __shared__ _Float16 sB[2][128 * 32];                                         \
  const int t = threadIdx.x;                                                   \
  const int bn = blockIdx.y, bm = blockIdx.x;                                  \
  const int lane = t & 63, wv = t >> 6, quad = lane >> 4, l16 = lane & 15;     \
  const int wm = wv & 1, wn = wv >> 1;                                         \
  const int srow = wv * 32 + (lane >> 2);                                      \
  const int scol = (((lane & 3) ^ ((lane >> 2) & 3))) * 8;                     \
  const int rq = (quad ^ (l16 & 3)) * 8;                                       \
  floatx4 acc[4][4] = {};                                                      \
  const _Float16* gA = AH + (size_t)(bm * 128 + srow) * 1024 + scol;           \
  const _Float16* gB = BH + (size_t)(bn * 128 + srow) * 1024 + scol;           \
  STAGE16(gA,         &sA[0][(wv * 32) * 32]);                                 \
  STAGE16(gA + 16384, &sA[0][(wv * 32 + 16) * 32]);                            \
  STAGE16(gB,         &sB[0][(wv * 32) * 32]);                                 \
  STAGE16(gB + 16384, &sB[0][(wv * 32 + 16) * 32]);                            \
  __syncthreads();                                                             \
  for (int kt = 0; kt < 32; kt++) {                                            \
    const int cur = kt & 1;                                                    \
    if (kt < 31) {                                                             \
      STAGE16(gA + (kt + 1) * 32,         &sA[cur ^ 1][(wv * 32) * 32]);       \
      STAGE16(gA + (kt + 1) * 32 + 16384, &sA[cur ^ 1][(wv * 32 + 16) * 32]);  \
      STAGE16(gB + (kt + 1) * 32,         &sB[cur ^ 1][(wv * 32) * 32]);       \
      STAGE16(gB + (kt + 1) * 32 + 16384, &sB[cur ^ 1][(wv * 32 + 16) * 32]);  \
    }                                                                          \
    half8 af[4], bf[4];                                                        \
    _Pragma("unroll")                                                          \
    for (int s = 0; s < 4; s++)                                                \
      af[s] = *(const half8*)&sA[cur][(wm * 64 + s * 16 + l16) * 32 + rq];     \
    _Pragma("unroll")                                                          \
    for (int u = 0; u < 4; u++)                                                \
      bf[u] = *(const half8*)&sB[cur][(wn * 64 + u * 16 + l16) * 32 + rq];     \
    _Pragma("unroll")                                                          \
    for (int s = 0; s < 4; s++)                                                \
      _Pragma("unroll")                                                        \
      for (int u = 0; u < 4; u++)                                              \
        acc[s][u] = __builtin_amdgcn_mfma_f32_16x16x32_f16(af[s], bf[u],       \
                                                           acc[s][u], 0, 0, 0); \
    __syncthreads();                                                           \
  }

// Batched QKV projection: blockIdx.z selects (A, W, mask, out). All f16 out.
__global__ __launch_bounds__(256) void qkv_gemm(
    const _Float16* __restrict__ Xq, const _Float16* __restrict__ Xk,
    const _Float16* __restrict__ Xv,
    const _Float16* __restrict__ Wqh, const _Float16* __restrict__ Wkh,
    const _Float16* __restrict__ Wvh,
    const int* __restrict__ mQ, const int* __restrict__ mK,
    _Float16* __restrict__ Qh, _Float16* __restrict__ Kh, _Float16* __restrict__ Vh)
{
  const int z = blockIdx.z;
  const _Float16* AH = (z == 0) ? Xq : (z == 1) ? Xk : Xv;
  const _Float16* BH = (z == 0) ? Wqh : (z == 1) ? Wkh : Wvh;
  const int* msk = (z == 0) ? mQ : mK;
  _Float16* out = (z == 0) ? Qh : (z == 1) ? Kh : Vh;
  GEMM97_CORE(AH, BH)
#pragma unroll
  for (int s = 0; s < 4; s++)
#pragma unroll
    for (int rr = 0; rr < 4; rr++) {
      const int row = bm * 128 + wm * 64 + s * 16 + quad * 4 + rr;
      const int m = msk[row];
#pragma unroll
      for (int u = 0; u < 4; u++)
        out[(size_t)row * 1024 + bn * 128 + wn * 64 + u * 16 + l16] =
            m ? (_Float16)0.0f : (_Float16)acc[s][u][rr];
    }
}

// ---------------------------------------------------------------------------
// 128x64 f16 GEMM (Wo), 2-phase double-buffered, same chunk-XOR swizzle.
// Epilogue: O2 = X1 + gelu_exact(X1 @ Wo^T).
// ---------------------------------------------------------------------------
__global__ __launch_bounds__(256) void gemm_wo(
    const _Float16* __restrict__ AH, const _Float16* __restrict__ BH,
    const float* __restrict__ X1, float* __restrict__ O2)
{
  __shared__ _Float16 sA[2][128 * 32];
  __shared__ _Float16 sB[2][64 * 32];
  const int t = threadIdx.x;
  const int bn = blockIdx.y, bm = blockIdx.x;
  const int lane = t & 63, wv = t >> 6, quad = lane >> 4, l16 = lane & 15;
  const int srowA = wv * 32 + (lane >> 2);
  const int srowB = wv * 16 + (lane >> 2);
  const int scol = (((lane & 3) ^ ((lane >> 2) & 3))) * 8;
  const int rq = (quad ^ (l16 & 3)) * 8;
  floatx4 acc[2][4] = {};
  const _Float16* gA = AH + (size_t)(bm * 128 + srowA) * 1024 + scol;
  const _Float16* gB = BH + (size_t)(bn * 64 + srowB) * 1024 + scol;
  STAGE16(gA,         &sA[0][(wv * 32) * 32]);
  STAGE16(gA + 16384, &sA[0][(wv * 32 + 16) * 32]);
  STAGE16(gB,         &sB[0][(wv * 16) * 32]);
  __syncthreads();
  for (int kt = 0; kt < 32; kt++) {
    const int cur = kt & 1;
    if (kt < 31) {
      STAGE16(gA + (kt + 1) * 32,         &sA[cur ^ 1][(wv * 32) * 32]);
      STAGE16(gA + (kt + 1) * 32 + 16384, &sA[cur ^ 1][(wv * 32 + 16) * 32]);
      STAGE16(gB + (kt + 1) * 32,         &sB[cur ^ 1][(wv * 16) * 32]);
    }
    half8 af[2], bf[4];
#pragma unroll
    for (int s = 0; s < 2; s++)
      af[s] = *(const half8*)&sA[cur][(wv * 32 + s * 16 + l16) * 32 + rq];
#pragma unroll
    for (int u = 0; u < 4; u++)
      bf[u] = *(const half8*)&sB[cur][(u * 16 + l16) * 32 + rq];
#pragma unroll
    for (int s = 0; s < 2; s++)
#pragma unroll
      for (int u = 0; u < 4; u++)
        acc[s][u] = __builtin_amdgcn_mfma_f32_16x16x32_f16(af[s], bf[u],
                                                           acc[s][u], 0, 0, 0);
    __syncthreads();
  }
#pragma unroll
  for (int s = 0; s < 2; s++)
#pragma unroll
    for (int rr = 0; rr < 4; rr++) {
      const int row = bm * 128 + wv * 32 + s * 16 + quad * 4 + rr;
#pragma unroll
      for (int u = 0; u < 4; u++) {
        const size_t idx = (size_t)row * 1024 + bn * 64 + u * 16 + l16;
        const float hv = acc[s][u][rr];
        const float ge = 0.5f * hv * (1.0f + erff(hv * 0.70710678118654752f));
        O2[idx] = X1[idx] + ge;   // masked rows: X1=0 -> 0 (matches ref)
      }
    }
}

// ---------------------------------------------------------------------------
// V transpose: Vh[b,k,h*64+d] -> Vt[(b*16+h)*64+d][k] (64x64 LDS tile).
// ---------------------------------------------------------------------------
__global__ __launch_bounds__(256) void v_transpose(
    const _Float16* __restrict__ Vh, _Float16* __restrict__ Vt)
{
  __shared__ _Float16 sT[64 * AST];
  const int t = threadIdx.x;
  const int kt = blockIdx.x, bh = blockIdx.y;
  const int b = bh >> 4, h = bh & 15;
  const int r = t >> 2, c0 = (t & 3) * 16;
  const _Float16* src = Vh + (size_t)(b * 1024 + kt * 64 + r) * 1024 + h * 64 + c0;
  *(half8*)&sT[r * AST + c0] = *(const half8*)src;
  *(half8*)&sT[r * AST + c0 + 8] = *(const half8*)(src + 8);
  __syncthreads();
  half8 o0, o1;
#pragma unroll
  for (int j = 0; j < 8; j++) o0[j] = sT[(c0 + j) * AST + r];
#pragma unroll
  for (int j = 0; j < 8; j++) o1[j] = sT[(c0 + 8 + j) * AST + r];
  _Float16* dst = Vt + ((size_t)bh * 64 + r) * 1024 + kt * 64 + c0;
  *(half8*)dst = o0;
  *(half8*)(dst + 8) = o1;
}

// ---------------------------------------------------------------------------
// MFMA flash attention (r1-proven 45.6us body + isolated exp2 fold):
//   - no-max softmax: p = exp2(s*C2 + bias); C2 = log2(e)/32; bias=-1e30
//     underflows to exactly 0 for masked k. 1 fewer VALU op per score.
//   - T14 reg prefetch of next K/V tile right after the second barrier.
//   - T5 setprio around both MFMA clusters.
// ---------------------------------------------------------------------------
__global__ __launch_bounds__(256) void attn_mfma3(
    const _Float16* __restrict__ Qh, const _Float16* __restrict__ Kh,
    const _Float16* __restrict__ Vt, const int* __restrict__ maskQ,
    const int* __restrict__ maskK, float* __restrict__ O1)
{
  __shared__ _Float16 sK[64 * AST];
  __shared__ _Float16 sV[64 * AST];
  __shared__ _Float16 sQP[64 * AST];   // Q tile at start; per-wave P rows in loop
  __shared__ float bias[1024];

  const int t = threadIdx.x;
  const int qt = blockIdx.x, bh = blockIdx.y;
  const int b = bh >> 4, h = bh & 15;
  const int q0 = qt * 64;
  const size_t base = (size_t)b * 1024;
  const int wv = t >> 6, lane = t & 63, quad = lane >> 4, l16 = lane & 15;
  const int r = t >> 2, c0 = (t & 3) * 16;

  // prologue: issue K/V tile-0 loads first (latency hides under bias+Q stage)
  const _Float16* kbase = Kh + (base + r) * 1024 + h * 64 + c0;
  const _Float16* vbase = Vt + ((size_t)bh * 64 + r) * 1024 + c0;
  half8 k0v = *(const half8*)kbase;
  half8 k1v = *(const half8*)(kbase + 8);
  half8 v0v = *(const half8*)vbase;
  half8 v1v = *(const half8*)(vbase + 8);

  for (int i = t; i < 1024; i += 256)
    bias[i] = maskK[b * 1024 + i] ? -1e30f : 0.0f;

  {  // stage Q tile (pure f16 copy)
    const _Float16* qp = Qh + (base + q0 + r) * 1024 + h * 64 + c0;
    *(half8*)&sQP[r * AST + c0] = *(const half8*)qp;
    *(half8*)&sQP[r * AST + c0 + 8] = *(const half8*)(qp + 8);
  }
  __syncthreads();

  // Q B-operand frags (wave's 16 q = wv*16 + l16), held in regs for whole loop
  const half8 bq0 = *(const half8*)&sQP[(wv * 16 + l16) * AST + quad * 8];
  const half8 bq1 = *(const half8*)&sQP[(wv * 16 + l16) * AST + 32 + quad * 8];

  float l_i = 0.0f;                    // per-lane: column q = wv*16 + l16
  floatx4 acc_o[4] = {};               // O C-layout: row q=quad*4+rr, col d=nt*16+l16

  const float C2 = 0.0450842200277985f;  // (1/32) * log2(e)

  for (int kt = 0; kt < 16; kt++) {
    __syncthreads();
    *(half8*)&sK[r * AST + c0]     = k0v;
    *(half8*)&sK[r * AST + c0 + 8] = k1v;
    *(half8*)&sV[r * AST + c0]     = v0v;
    *(half8*)&sV[r * AST + c0 + 8] = v1v;
    __syncthreads();

    // T14: prefetch next K/V tile into regs; latency hidden by compute below
    if (kt < 15) {
      const _Float16* kp = kbase + (size_t)(kt + 1) * 64 * 1024;
      const _Float16* vp = vbase + (kt + 1) * 64;
      k0v = *(const half8*)kp;
      k1v = *(const half8*)(kp + 8);
      v0v = *(const half8*)vp;
      v1v = *(const half8*)(vp + 8);
    }

    // S^T[k][q]: A = K rows, B = Q rows. s[mt][rr]: k = mt*16+quad*4+rr, q = wv*16+l16
    floatx4 s[4] = {};
    __builtin_amdgcn_s_setprio(1);
#pragma unroll
    for (int mt = 0; mt < 4; mt++) {
      const half8 ak0 = *(const half8*)&sK[(mt * 16 + l16) * AST + quad * 8];
      const half8 ak1 = *(const half8*)&sK[(mt * 16 + l16) * AST + 32 + quad * 8];
      s[mt] = __builtin_amdgcn_mfma_f32_16x16x32_f16(ak0, bq0, s[mt], 0, 0, 0);
      s[mt] = __builtin_amdgcn_mfma_f32_16x16x32_f16(ak1, bq1, s[mt], 0, 0, 0);
    }
    __builtin_amdgcn_s_setprio(0);

    // exact softmax numerator, no max-subtraction (scores bounded << 88):
    // masked k: bias=-1e30 -> exp2 underflows to exactly 0.
    float rsum = 0.0f;
#pragma unroll
    for (int mt = 0; mt < 4; mt++) {
      const float4 b4 = *(const float4*)&bias[kt * 64 + mt * 16 + quad * 4];
      const float p0 = __builtin_amdgcn_exp2f(s[mt][0] * C2 + b4.x);
      const float p1 = __builtin_amdgcn_exp2f(s[mt][1] * C2 + b4.y);
      const float p2 = __builtin_amdgcn_exp2f(s[mt][2] * C2 + b4.z);
      const float p3 = __builtin_amdgcn_exp2f(s[mt][3] * C2 + b4.w);
      s[mt][0] = p0; s[mt][1] = p1; s[mt][2] = p2; s[mt][3] = p3;
      rsum += (p0 + p1) + (p2 + p3);
    }
    rsum += __shfl_xor(rsum, 16);
    rsum += __shfl_xor(rsum, 32);
    l_i += rsum;

    // P^T -> wave-private LDS rows q, packed half4 along k (4x b64 writes)
#pragma unroll
    for (int mt = 0; mt < 4; mt++) {
      half4v pv;
      pv[0] = (_Float16)s[mt][0]; pv[1] = (_Float16)s[mt][1];
      pv[2] = (_Float16)s[mt][2]; pv[3] = (_Float16)s[mt][3];
      *(half4v*)&sQP[(wv * 16 + l16) * AST + mt * 16 + quad * 4] = pv;
    }

    // PV: A = P rows q, B = V^T rows d
    const half8 ap0 = *(const half8*)&sQP[(wv * 16 + l16) * AST + quad * 8];
    const half8 ap1 = *(const half8*)&sQP[(wv * 16 + l16) * AST + 32 + quad * 8];
    __builtin_amdgcn_s_setprio(1);
#pragma unroll
    for (int nt = 0; nt < 4; nt++) {
      const half8 bv0 = *(const half8*)&sV[(nt * 16 + l16) * AST + quad * 8];
      const half8 bv1 = *(const half8*)&sV[(nt * 16 + l16) * AST + 32 + quad * 8];
      acc_o[nt] = __builtin_amdgcn_mfma_f32_16x16x32_f16(ap0, bv0, acc_o[nt], 0, 0, 0);
      acc_o[nt] = __builtin_amdgcn_mfma_f32_16x16x32_f16(ap1, bv1, acc_o[nt], 0, 0, 0);
    }
    __builtin_amdgcn_s_setprio(0);
  }

  // epilogue: O1 = maskQ ? 0 : Qh + O/l   (l broadcast column->row)
  float il[4];
#pragma unroll
  for (int rr = 0; rr < 4; rr++) {
    const float lq = __shfl(l_i, quad * 4 + rr);
    il[rr] = (lq > 0.0f) ? 1.0f / lq : 0.0f;
  }
#pragma unroll
  for (int rr = 0; rr < 4; rr++) {
    const int row = q0 + wv * 16 + quad * 4 + rr;
    const int mq = maskQ[b * 1024 + row];
#pragma unroll
    for (int nt = 0; nt < 4; nt++) {
      const size_t gi = (base + row) * 1024 + h * 64 + nt * 16 + l16;
      O1[gi] = mq ? 0.0f : ((float)Qh[gi] + acc_o[nt][rr] * il[rr]);
    }
  }
}

// ---------------------------------------------------------------------------
// LayerNorm (one row of 1024 per block), fp32 in; fp32 out (+ optional f16).
// ---------------------------------------------------------------------------
__device__ __forceinline__ void ln_stats(float4 x, int t, float* mean, float* rinv) {
  float s = x.x + x.y + x.z + x.w;
  float s2 = x.x * x.x + x.y * x.y + x.z * x.z + x.w * x.w;
#pragma unroll
  for (int off = 32; off >= 1; off >>= 1) { s += __shfl_xor(s, off); s2 += __shfl_xor(s2, off); }
  __shared__ float red[8];
  __shared__ float sm[2];
  const int wv = t >> 6, lane = t & 63;
  if (lane == 0) { red[wv] = s; red[4 + wv] = s2; }
  __syncthreads();
  if (t == 0) {
    const float S = red[0] + red[1] + red[2] + red[3];
    const float S2 = red[4] + red[5] + red[6] + red[7];
    const float m = S * (1.0f / 1024.0f);
    const float v = S2 * (1.0f / 1024.0f) - m * m;
    sm[0] = m; sm[1] = rsqrtf(v + 1e-5f);
  }
  __syncthreads();
  *mean = sm[0]; *rinv = sm[1];
}

__global__ __launch_bounds__(256) void ln_f32(
    const float* __restrict__ X, const float* __restrict__ g,
    const float* __restrict__ bta, const int* __restrict__ mask,
    float* __restrict__ out)
{
  const int rr = blockIdx.x, t = threadIdx.x, c = 4 * t;
  const float4 x = *(const float4*)&X[(size_t)rr * 1024 + c];
  float mean, ri;
  ln_stats(x, t, &mean, &ri);
  const int msk = mask[rr];
  const float4 gg = *(const float4*)&g[c];
  const float4 bb = *(const float4*)&bta[c];
  float4 o;
  o.x = msk ? 0.f : (x.x - mean) * ri * gg.x + bb.x;
  o.y = msk ? 0.f : (x.y - mean) * ri * gg.y + bb.y;
  o.z = msk ? 0.f : (x.z - mean) * ri * gg.z + bb.z;
  o.w = msk ? 0.f : (x.w - mean) * ri * gg.w + bb.w;
  *(float4*)&out[(size_t)rr * 1024 + c] = o;
}

__global__ __launch_bounds__(256) void ln_f32h(
    const float* __restrict__ X, const float* __restrict__ g,
    const float* __restrict__ bta, const int* __restrict__ mask,
    float* __restrict__ out, _Float16* __restrict__ outh)
{
  const int rr = blockIdx.x, t = threadIdx.x, c = 4 * t;
  const float4 x = *(const float4*)&X[(size_t)rr * 1024 + c];
  float mean, ri;
  ln_stats(x, t, &mean, &ri);
  const int msk = mask[rr];
  const float4 gg = *(const float4*)&g[c];
  const float4 bb = *(const float4*)&bta[c];
  float4 o;
  o.x = msk ? 0.f : (x.x - mean) * ri * gg.x + bb.x;
  o.y = msk ? 0.f : (x.y - mean) * ri * gg.y + bb.y;
  o.z = msk ? 0.f : (x.z - mean) * ri * gg.z + bb.z;
  o.w = msk ? 0.f : (x.w - mean) * ri * gg.w + bb.w;
  const size_t idx = (size_t)rr * 1024 + c;
  *(float4*)&out[idx] = o;
  half4v hh;
  hh[0] = (_Float16)o.x; hh[1] = (_Float16)o.y;
  hh[2] = (_Float16)o.z; hh[3] = (_Float16)o.w;
  *(half4v*)&outh[idx] = hh;
}

// ---------------------------------------------------------------------------
extern "C" void kernel_launch(void* const* d_in, const int* in_sizes, int n_in,
                              void* d_out, int out_size, void* d_ws, size_t ws_size,
                              hipStream_t stream)
{
  const float* Q  = (const float*)d_in[0];
  const float* K  = (const float*)d_in[1];
  const float* V  = (const float*)d_in[2];
  const float* Wq = (const float*)d_in[3];
  const float* Wk = (const float*)d_in[4];
  const float* Wv = (const float*)d_in[5];
  const float* Wo = (const float*)d_in[6];
  const float* g1 = (const float*)d_in[7];
  const float* b1 = (const float*)d_in[8];
  const float* g2 = (const float*)d_in[9];
  const float* b2 = (const float*)d_in[10];
  float* out = (float*)d_out;

  char* base = (char*)d_ws;
  const size_t MB_ = 1024 * 1024;
  _Float16* Xq  = (_Float16*)(base +  0 * MB_);   // [0,8)
  _Float16* Xk  = (_Float16*)(base +  8 * MB_);   // [8,16)
  _Float16* Xv  = (_Float16*)(base + 16 * MB_);   // [16,24)
  _Float16* Wqh = (_Float16*)(base + 24 * MB_);   // [24,26)
  _Float16* Wkh = (_Float16*)(base + 26 * MB_);   // [26,28)
  _Float16* Wvh = (_Float16*)(base + 28 * MB_);   // [28,30)
  _Float16* Woh = (_Float16*)(base + 30 * MB_);   // [30,32)
  _Float16* Qh  = (_Float16*)(base + 32 * MB_);   // [32,40)
  _Float16* Kh  = (_Float16*)(base + 40 * MB_);   // [40,48)
  _Float16* Vh  = (_Float16*)(base + 48 * MB_);   // [48,56)
  _Float16* Vt  = (_Float16*)(base + 56 * MB_);   // [56,64)
  float*    O1  = (float*)(base + 64 * MB_);      // [64,80)
  int*      mQ  = (int*)(base + 80 * MB_);
  int*      mK  = mQ + NTOK;                      // peak: 80 MB + 32 KB (r8-proven)
  // post-attention aliases (source regions dead):
  float*    X1  = (float*)(base + 0 * MB_);       // over Xq∪Xk
  _Float16* X1h = (_Float16*)(base + 16 * MB_);   // over Xv
  float*    O2  = (float*)(base + 32 * MB_);      // over Qh∪Kh

  const dim3 bb(256);
  cvt_all<<<dim3(8208), bb, 0, stream>>>(Q, K, V, Wq, Wk, Wv, Wo,
                                         (const int*)d_in[11], (const int*)d_in[12],
                                         Xq, Xk, Xv, Wqh, Wkh, Wvh, Woh, mQ, mK);
  qkv_gemm<<<dim3(32, 8, 3), bb, 0, stream>>>(Xq, Xk, Xv, Wqh, Wkh, Wvh,
                                              mQ, mK, Qh, Kh, Vh);
  v_transpose<<<dim3(16, 64), bb, 0, stream>>>(Vh, Vt);
  attn_mfma3<<<dim3(16, 64), bb, 0, stream>>>(Qh, Kh, Vt, mQ, mK, O1);
  ln_f32h<<<dim3(4096), bb, 0, stream>>>(O1, g1, b1, mQ, X1, X1h);
  gemm_wo<<<dim3(32, 16), bb, 0, stream>>>(X1h, Woh, X1, O2);
  ln_f32<<<dim3(4096), bb, 0, stream>>>(O2, g2, b2, mQ, out);
}

// Round 6
// 248.369 us; speedup vs baseline: 1.1064x; 1.0078x over previous
//
#include <hip/hip_runtime.h>

// Problem constants (B=4, N=1024, DIM=1024, H=16, DH=64)
// Dtype model (r5-proven): tensor inputs fp32, masks int32, d_out fp32.
#define NTOK 4096
#define AST 72   // attn LDS row stride in halves (144 B: 16B-aligned, bank-stride 4)

typedef _Float16 half4v __attribute__((ext_vector_type(4)));
typedef _Float16 half8 __attribute__((ext_vector_type(8)));
typedef float floatx4 __attribute__((ext_vector_type(4)));

__device__ __forceinline__ half8 cvt8(float4 a, float4 b) {
  half8 h;
  h[0] = (_Float16)a.x; h[1] = (_Float16)a.y; h[2] = (_Float16)a.z; h[3] = (_Float16)a.w;
  h[4] = (_Float16)b.x; h[5] = (_Float16)b.y; h[6] = (_Float16)b.z; h[7] = (_Float16)b.w;
  return h;
}

#if defined(__has_builtin)
#if __has_builtin(__builtin_amdgcn_global_load_lds)
#define HAS_GLL 1
#endif
#endif

#ifdef HAS_GLL
#define STAGE16(gp, lp)                                                        \
  __builtin_amdgcn_global_load_lds(                                           \
      (const __attribute__((address_space(1))) void*)(gp),                     \
      (__attribute__((address_space(3))) void*)(lp), 16, 0, 0)
#else
#define STAGE16(gp, lp)                                                        \
  do { *(half8*)((_Float16*)(lp) + lane * 8) = *(const half8*)(gp); } while (0)
#endif

// ---------------------------------------------------------------------------
// Mask canonicalization (r3 proved masks arrive int32; kept for robustness).
// ---------------------------------------------------------------------------
__device__ __forceinline__ int mask_is_bytes(const int* p) {
  int bad = 0;
#pragma unroll
  for (int i = 0; i < 64; i++) bad |= (((unsigned int)p[i]) > 1u);
  return bad;
}

// ---------------------------------------------------------------------------
// One-shot fp32 -> f16 conversion of GEMM operands (Q,K,V inputs + 4 weights)
// + mask canonicalization fused into the same launch (blocks >= 8192).
// ---------------------------------------------------------------------------
__global__ __launch_bounds__(256) void cvt_all(
    const float* __restrict__ Q, const float* __restrict__ K, const float* __restrict__ V,
    const float* __restrict__ Wq, const float* __restrict__ Wk, const float* __restrict__ Wv,
    const float* __restrict__ Wo,
    const int* __restrict__ srcQ, const int* __restrict__ srcK,
    _Float16* __restrict__ Xq, _Float16* __restrict__ Xk, _Float16* __restrict__ Xv,
    _Float16* __restrict__ Wqh, _Float16* __restrict__ Wkh, _Float16* __restrict__ Wvh,
    _Float16* __restrict__ Woh,
    int* __restrict__ dstQ, int* __restrict__ dstK)
{
  const int blk = blockIdx.x;
  if (blk >= 8192) {  // fused mask_prep: 16 blocks x 256 = 4096 tokens
    const int t = (blk - 8192) * 256 + threadIdx.x;
    const int bq = mask_is_bytes(srcQ);
    const int bk = mask_is_bytes(srcK);
    dstQ[t] = bq ? (int)((const unsigned char*)srcQ)[t] : srcQ[t];
    dstK[t] = bk ? (int)((const unsigned char*)srcK)[t] : srcK[t];
    return;
  }
  const float* src; _Float16* dst; size_t off;
  if      (blk < 2048) { src = Q;  dst = Xq;  off = (size_t)blk * 2048; }
  else if (blk < 4096) { src = K;  dst = Xk;  off = (size_t)(blk - 2048) * 2048; }
  else if (blk < 6144) { src = V;  dst = Xv;  off = (size_t)(blk - 4096) * 2048; }
  else if (blk < 6656) { src = Wq; dst = Wqh; off = (size_t)(blk - 6144) * 2048; }
  else if (blk < 7168) { src = Wk; dst = Wkh; off = (size_t)(blk - 6656) * 2048; }
  else if (blk < 7680) { src = Wv; dst = Wvh; off = (size_t)(blk - 7168) * 2048; }
  else                 { src = Wo; dst = Woh; off = (size_t)(blk - 7680) * 2048; }
  const size_t i = off + (size_t)threadIdx.x * 8;
  const float4 a = *(const float4*)(src + i);
  const float4 b = *(const float4*)(src + i + 4);
  *(half8*)(dst + i) = cvt8(a, b);
}

// ---------------------------------------------------------------------------
// 128x128 f16 GEMM core, 2-phase double-buffered (T3-min recipe), ONE barrier
// per K-step. Linear LDS layout (r5's chunk-XOR swizzle removed: A/B'd at
// zero conflict delta and +1.9us on qkv -- proven-negative graft).
// ---------------------------------------------------------------------------
#define GEMM97_CORE(AH, BH)                                                    \
  __shared__ _Float16 sA[2][128 * 32];                                         \
  __shared__ _Float16 sB[2][128 * 32];                                         \
  const int t = threadIdx.x;                                                   \
  const int bn = blockIdx.y, bm = blockIdx.x;                                  \
  const int lane = t & 63, wv = t >> 6, quad = lane >> 4, l16 = lane & 15;     \
  const int wm = wv & 1, wn = wv >> 1;                                         \
  const int srow = wv * 32 + (lane >> 2);                                      \
  const int scol = (lane & 3) * 8;                                             \
  floatx4 acc[4][4] = {};                                                      \
  const _Float16* gA = AH + (size_t)(bm * 128 + srow) * 1024 + scol;           \
  const _Float16* gB = BH + (size_t)(bn * 128 + srow) * 1024 + scol;           \
  STAGE16(gA,         &sA[0][(wv * 32) * 32]);                                 \
  STAGE16(gA + 16384, &sA[0][(wv * 32 + 16) * 32]);                            \
  STAGE16(gB,         &sB[0][(wv * 32) * 32]);                                 \
  STAGE16(gB + 16384, &sB[0][(wv * 32 + 16) * 32]);                            \
  __syncthreads();                                                             \
  for (int kt = 0; kt < 32; kt++) {                                            \
    const int cur = kt & 1;                                                    \
    if (kt < 31) {                                                             \
      STAGE16(gA + (kt + 1) * 32,         &sA[cur ^ 1][(wv * 32) * 32]);       \
      STAGE16(gA + (kt + 1) * 32 + 16384, &sA[cur ^ 1][(wv * 32 + 16) * 32]);  \
      STAGE16(gB + (kt + 1) * 32,         &sB[cur ^ 1][(wv * 32) * 32]);       \
      STAGE16(gB + (kt + 1) * 32 + 16384, &sB[cur ^ 1][(wv * 32 + 16) * 32]);  \
    }                                                                          \
    half8 af[4], bf[4];                                                        \
    _Pragma("unroll")                                                          \
    for (int s = 0; s < 4; s++)                                                \
      af[s] = *(const half8*)&sA[cur][(wm * 64 + s * 16 + l16) * 32 + quad * 8]; \
    _Pragma("unroll")                                                          \
    for (int u = 0; u < 4; u++)                                                \
      bf[u] = *(const half8*)&sB[cur][(wn * 64 + u * 16 + l16) * 32 + quad * 8]; \
    _Pragma("unroll")                                                          \
    for (int s = 0; s < 4; s++)                                                \
      _Pragma("unroll")                                                        \
      for (int u = 0; u < 4; u++)                                              \
        acc[s][u] = __builtin_amdgcn_mfma_f32_16x16x32_f16(af[s], bf[u],       \
                                                           acc[s][u], 0, 0, 0); \
    __syncthreads();                                                           \
  }

// Batched QKV projection: blockIdx.z selects (A, W, mask, out). All f16 out.
__global__ __launch_bounds__(256) void qkv_gemm(
    const _Float16* __restrict__ Xq, const _Float16* __restrict__ Xk,
    const _Float16* __restrict__ Xv,
    const _Float16* __restrict__ Wqh, const _Float16* __restrict__ Wkh,
    const _Float16* __restrict__ Wvh,
    const int* __restrict__ mQ, const int* __restrict__ mK,
    _Float16* __restrict__ Qh, _Float16* __restrict__ Kh, _Float16* __restrict__ Vh)
{
  const int z = blockIdx.z;
  const _Float16* AH = (z == 0) ? Xq : (z == 1) ? Xk : Xv;
  const _Float16* BH = (z == 0) ? Wqh : (z == 1) ? Wkh : Wvh;
  const int* msk = (z == 0) ? mQ : mK;
  _Float16* out = (z == 0) ? Qh : (z == 1) ? Kh : Vh;
  GEMM97_CORE(AH, BH)
#pragma unroll
  for (int s = 0; s < 4; s++)
#pragma unroll
    for (int rr = 0; rr < 4; rr++) {
      const int row = bm * 128 + wm * 64 + s * 16 + quad * 4 + rr;
      const int m = msk[row];
#pragma unroll
      for (int u = 0; u < 4; u++)
        out[(size_t)row * 1024 + bn * 128 + wn * 64 + u * 16 + l16] =
            m ? (_Float16)0.0f : (_Float16)acc[s][u][rr];
    }
}

// ---------------------------------------------------------------------------
// 128x64 f16 GEMM (Wo), 2-phase double-buffered, linear LDS.
// Epilogue: O2 = X1 + gelu_exact(X1 @ Wo^T).
// ---------------------------------------------------------------------------
__global__ __launch_bounds__(256) void gemm_wo(
    const _Float16* __restrict__ AH, const _Float16* __restrict__ BH,
    const float* __restrict__ X1, float* __restrict__ O2)
{
  __shared__ _Float16 sA[2][128 * 32];
  __shared__ _Float16 sB[2][64 * 32];
  const int t = threadIdx.x;
  const int bn = blockIdx.y, bm = blockIdx.x;
  const int lane = t & 63, wv = t >> 6, quad = lane >> 4, l16 = lane & 15;
  const int srowA = wv * 32 + (lane >> 2);
  const int srowB = wv * 16 + (lane >> 2);
  const int scol = (lane & 3) * 8;
  floatx4 acc[2][4] = {};
  const _Float16* gA = AH + (size_t)(bm * 128 + srowA) * 1024 + scol;
  const _Float16* gB = BH + (size_t)(bn * 64 + srowB) * 1024 + scol;
  STAGE16(gA,         &sA[0][(wv * 32) * 32]);
  STAGE16(gA + 16384, &sA[0][(wv * 32 + 16) * 32]);
  STAGE16(gB,         &sB[0][(wv * 16) * 32]);
  __syncthreads();
  for (int kt = 0; kt < 32; kt++) {
    const int cur = kt & 1;
    if (kt < 31) {
      STAGE16(gA + (kt + 1) * 32,         &sA[cur ^ 1][(wv * 32) * 32]);
      STAGE16(gA + (kt + 1) * 32 + 16384, &sA[cur ^ 1][(wv * 32 + 16) * 32]);
      STAGE16(gB + (kt + 1) * 32,         &sB[cur ^ 1][(wv * 16) * 32]);
    }
    half8 af[2], bf[4];
#pragma unroll
    for (int s = 0; s < 2; s++)
      af[s] = *(const half8*)&sA[cur][(wv * 32 + s * 16 + l16) * 32 + quad * 8];
#pragma unroll
    for (int u = 0; u < 4; u++)
      bf[u] = *(const half8*)&sB[cur][(u * 16 + l16) * 32 + quad * 8];
#pragma unroll
    for (int s = 0; s < 2; s++)
#pragma unroll
      for (int u = 0; u < 4; u++)
        acc[s][u] = __builtin_amdgcn_mfma_f32_16x16x32_f16(af[s], bf[u],
                                                           acc[s][u], 0, 0, 0);
    __syncthreads();
  }
#pragma unroll
  for (int s = 0; s < 2; s++)
#pragma unroll
    for (int rr = 0; rr < 4; rr++) {
      const int row = bm * 128 + wv * 32 + s * 16 + quad * 4 + rr;
#pragma unroll
      for (int u = 0; u < 4; u++) {
        const size_t idx = (size_t)row * 1024 + bn * 64 + u * 16 + l16;
        const float hv = acc[s][u][rr];
        const float ge = 0.5f * hv * (1.0f + erff(hv * 0.70710678118654752f));
        O2[idx] = X1[idx] + ge;   // masked rows: X1=0 -> 0 (matches ref)
      }
    }
}

// ---------------------------------------------------------------------------
// V transpose: Vh[b,k,h*64+d] -> Vt[(b*16+h)*64+d][k] (64x64 LDS tile).
// ---------------------------------------------------------------------------
__global__ __launch_bounds__(256) void v_transpose(
    const _Float16* __restrict__ Vh, _Float16* __restrict__ Vt)
{
  __shared__ _Float16 sT[64 * AST];
  const int t = threadIdx.x;
  const int kt = blockIdx.x, bh = blockIdx.y;
  const int b = bh >> 4, h = bh & 15;
  const int r = t >> 2, c0 = (t & 3) * 16;
  const _Float16* src = Vh + (size_t)(b * 1024 + kt * 64 + r) * 1024 + h * 64 + c0;
  *(half8*)&sT[r * AST + c0] = *(const half8*)src;
  *(half8*)&sT[r * AST + c0 + 8] = *(const half8*)(src + 8);
  __syncthreads();
  half8 o0, o1;
#pragma unroll
  for (int j = 0; j < 8; j++) o0[j] = sT[(c0 + j) * AST + r];
#pragma unroll
  for (int j = 0; j < 8; j++) o1[j] = sT[(c0 + 8 + j) * AST + r];
  _Float16* dst = Vt + ((size_t)bh * 64 + r) * 1024 + kt * 64 + c0;
  *(half8*)dst = o0;
  *(half8*)(dst + 8) = o1;
}

// ---------------------------------------------------------------------------
// MFMA flash attention (r1-proven body + exp2 fold, both harness-verified):
//   - no-max softmax: p = exp2(s*C2 + bias); C2 = log2(e)/32; bias=-1e30
//     underflows to exactly 0 for masked k.
//   - T14 reg prefetch of next K/V tile right after the second barrier.
//   - T5 setprio around both MFMA clusters.
// ---------------------------------------------------------------------------
__global__ __launch_bounds__(256) void attn_mfma3(
    const _Float16* __restrict__ Qh, const _Float16* __restrict__ Kh,
    const _Float16* __restrict__ Vt, const int* __restrict__ maskQ,
    const int* __restrict__ maskK, float* __restrict__ O1)
{
  __shared__ _Float16 sK[64 * AST];
  __shared__ _Float16 sV[64 * AST];
  __shared__ _Float16 sQP[64 * AST];   // Q tile at start; per-wave P rows in loop
  __shared__ float bias[1024];

  const int t = threadIdx.x;
  const int qt = blockIdx.x, bh = blockIdx.y;
  const int b = bh >> 4, h = bh & 15;
  const int q0 = qt * 64;
  const size_t base = (size_t)b * 1024;
  const int wv = t >> 6, lane = t & 63, quad = lane >> 4, l16 = lane & 15;
  const int r = t >> 2, c0 = (t & 3) * 16;

  // prologue: issue K/V tile-0 loads first (latency hides under bias+Q stage)
  const _Float16* kbase = Kh + (base + r) * 1024 + h * 64 + c0;
  const _Float16* vbase = Vt + ((size_t)bh * 64 + r) * 1024 + c0;
  half8 k0v = *(const half8*)kbase;
  half8 k1v = *(const half8*)(kbase + 8);
  half8 v0v = *(const half8*)vbase;
  half8 v1v = *(const half8*)(vbase + 8);

  for (int i = t; i < 1024; i += 256)
    bias[i] = maskK[b * 1024 + i] ? -1e30f : 0.0f;

  {  // stage Q tile (pure f16 copy)
    const _Float16* qp = Qh + (base + q0 + r) * 1024 + h * 64 + c0;
    *(half8*)&sQP[r * AST + c0] = *(const half8*)qp;
    *(half8*)&sQP[r * AST + c0 + 8] = *(const half8*)(qp + 8);
  }
  __syncthreads();

  // Q B-operand frags (wave's 16 q = wv*16 + l16), held in regs for whole loop
  const half8 bq0 = *(const half8*)&sQP[(wv * 16 + l16) * AST + quad * 8];
  const half8 bq1 = *(const half8*)&sQP[(wv * 16 + l16) * AST + 32 + quad * 8];

  float l_i = 0.0f;                    // per-lane: column q = wv*16 + l16
  floatx4 acc_o[4] = {};               // O C-layout: row q=quad*4+rr, col d=nt*16+l16

  const float C2 = 0.0450842200277985f;  // (1/32) * log2(e)

  for (int kt = 0; kt < 16; kt++) {
    __syncthreads();
    *(half8*)&sK[r * AST + c0]     = k0v;
    *(half8*)&sK[r * AST + c0 + 8] = k1v;
    *(half8*)&sV[r * AST + c0]     = v0v;
    *(half8*)&sV[r * AST + c0 + 8] = v1v;
    __syncthreads();

    // T14: prefetch next K/V tile into regs; latency hidden by compute below
    if (kt < 15) {
      const _Float16* kp = kbase + (size_t)(kt + 1) * 64 * 1024;
      const _Float16* vp = vbase + (kt + 1) * 64;
      k0v = *(const half8*)kp;
      k1v = *(const half8*)(kp + 8);
      v0v = *(const half8*)vp;
      v1v = *(const half8*)(vp + 8);
    }

    // S^T[k][q]: A = K rows, B = Q rows. s[mt][rr]: k = mt*16+quad*4+rr, q = wv*16+l16
    floatx4 s[4] = {};
    __builtin_amdgcn_s_setprio(1);
#pragma unroll
    for (int mt = 0; mt < 4; mt++) {
      const half8 ak0 = *(const half8*)&sK[(mt * 16 + l16) * AST + quad * 8];
      const half8 ak1 = *(const half8*)&sK[(mt * 16 + l16) * AST + 32 + quad * 8];
      s[mt] = __builtin_amdgcn_mfma_f32_16x16x32_f16(ak0, bq0, s[mt], 0, 0, 0);
      s[mt] = __builtin_amdgcn_mfma_f32_16x16x32_f16(ak1, bq1, s[mt], 0, 0, 0);
    }
    __builtin_amdgcn_s_setprio(0);

    // exact softmax numerator, no max-subtraction (scores bounded << 88):
    // masked k: bias=-1e30 -> exp2 underflows to exactly 0.
    float rsum = 0.0f;
#pragma unroll
    for (int mt = 0; mt < 4; mt++) {
      const float4 b4 = *(const float4*)&bias[kt * 64 + mt * 16 + quad * 4];
      const float p0 = __builtin_amdgcn_exp2f(s[mt][0] * C2 + b4.x);
      const float p1 = __builtin_amdgcn_exp2f(s[mt][1] * C2 + b4.y);
      const float p2 = __builtin_amdgcn_exp2f(s[mt][2] * C2 + b4.z);
      const float p3 = __builtin_amdgcn_exp2f(s[mt][3] * C2 + b4.w);
      s[mt][0] = p0; s[mt][1] = p1; s[mt][2] = p2; s[mt][3] = p3;
      rsum += (p0 + p1) + (p2 + p3);
    }
    rsum += __shfl_xor(rsum, 16);
    rsum += __shfl_xor(rsum, 32);
    l_i += rsum;

    // P^T -> wave-private LDS rows q, packed half4 along k (4x b64 writes)
#pragma unroll
    for (int mt = 0; mt < 4; mt++) {
      half4v pv;
      pv[0] = (_Float16)s[mt][0]; pv[1] = (_Float16)s[mt][1];
      pv[2] = (_Float16)s[mt][2]; pv[3] = (_Float16)s[mt][3];
      *(half4v*)&sQP[(wv * 16 + l16) * AST + mt * 16 + quad * 4] = pv;
    }

    // PV: A = P rows q, B = V^T rows d
    const half8 ap0 = *(const half8*)&sQP[(wv * 16 + l16) * AST + quad * 8];
    const half8 ap1 = *(const half8*)&sQP[(wv * 16 + l16) * AST + 32 + quad * 8];
    __builtin_amdgcn_s_setprio(1);
#pragma unroll
    for (int nt = 0; nt < 4; nt++) {
      const half8 bv0 = *(const half8*)&sV[(nt * 16 + l16) * AST + quad * 8];
      const half8 bv1 = *(const half8*)&sV[(nt * 16 + l16) * AST + 32 + quad * 8];
      acc_o[nt] = __builtin_amdgcn_mfma_f32_16x16x32_f16(ap0, bv0, acc_o[nt], 0, 0, 0);
      acc_o[nt] = __builtin_amdgcn_mfma_f32_16x16x32_f16(ap1, bv1, acc_o[nt], 0, 0, 0);
    }
    __builtin_amdgcn_s_setprio(0);
  }

  // epilogue: O1 = maskQ ? 0 : Qh + O/l   (l broadcast column->row)
  float il[4];
#pragma unroll
  for (int rr = 0; rr < 4; rr++) {
    const float lq = __shfl(l_i, quad * 4 + rr);
    il[rr] = (lq > 0.0f) ? 1.0f / lq : 0.0f;
  }
#pragma unroll
  for (int rr = 0; rr < 4; rr++) {
    const int row = q0 + wv * 16 + quad * 4 + rr;
    const int mq = maskQ[b * 1024 + row];
#pragma unroll
    for (int nt = 0; nt < 4; nt++) {
      const size_t gi = (base + row) * 1024 + h * 64 + nt * 16 + l16;
      O1[gi] = mq ? 0.0f : ((float)Qh[gi] + acc_o[nt][rr] * il[rr]);
    }
  }
}

// ---------------------------------------------------------------------------
// LayerNorm (one row of 1024 per block), fp32 in; fp32 out (+ optional f16).
// ---------------------------------------------------------------------------
__device__ __forceinline__ void ln_stats(float4 x, int t, float* mean, float* rinv) {
  float s = x.x + x.y + x.z + x.w;
  float s2 = x.x * x.x + x.y * x.y + x.z * x.z + x.w * x.w;
#pragma unroll
  for (int off = 32; off >= 1; off >>= 1) { s += __shfl_xor(s, off); s2 += __shfl_xor(s2, off); }
  __shared__ float red[8];
  __shared__ float sm[2];
  const int wv = t >> 6, lane = t & 63;
  if (lane == 0) { red[wv] = s; red[4 + wv] = s2; }
  __syncthreads();
  if (t == 0) {
    const float S = red[0] + red[1] + red[2] + red[3];
    const float S2 = red[4] + red[5] + red[6] + red[7];
    const float m = S * (1.0f / 1024.0f);
    const float v = S2 * (1.0f / 1024.0f) - m * m;
    sm[0] = m; sm[1] = rsqrtf(v + 1e-5f);
  }
  __syncthreads();
  *mean = sm[0]; *rinv = sm[1];
}

__global__ __launch_bounds__(256) void ln_f32(
    const float* __restrict__ X, const float* __restrict__ g,
    const float* __restrict__ bta, const int* __restrict__ mask,
    float* __restrict__ out)
{
  const int rr = blockIdx.x, t = threadIdx.x, c = 4 * t;
  const float4 x = *(const float4*)&X[(size_t)rr * 1024 + c];
  float mean, ri;
  ln_stats(x, t, &mean, &ri);
  const int msk = mask[rr];
  const float4 gg = *(const float4*)&g[c];
  const float4 bb = *(const float4*)&bta[c];
  float4 o;
  o.x = msk ? 0.f : (x.x - mean) * ri * gg.x + bb.x;
  o.y = msk ? 0.f : (x.y - mean) * ri * gg.y + bb.y;
  o.z = msk ? 0.f : (x.z - mean) * ri * gg.z + bb.z;
  o.w = msk ? 0.f : (x.w - mean) * ri * gg.w + bb.w;
  *(float4*)&out[(size_t)rr * 1024 + c] = o;
}

__global__ __launch_bounds__(256) void ln_f32h(
    const float* __restrict__ X, const float* __restrict__ g,
    const float* __restrict__ bta, const int* __restrict__ mask,
    float* __restrict__ out, _Float16* __restrict__ outh)
{
  const int rr = blockIdx.x, t = threadIdx.x, c = 4 * t;
  const float4 x = *(const float4*)&X[(size_t)rr * 1024 + c];
  float mean, ri;
  ln_stats(x, t, &mean, &ri);
  const int msk = mask[rr];
  const float4 gg = *(const float4*)&g[c];
  const float4 bb = *(const float4*)&bta[c];
  float4 o;
  o.x = msk ? 0.f : (x.x - mean) * ri * gg.x + bb.x;
  o.y = msk ? 0.f : (x.y - mean) * ri * gg.y + bb.y;
  o.z = msk ? 0.f : (x.z - mean) * ri * gg.z + bb.z;
  o.w = msk ? 0.f : (x.w - mean) * ri * gg.w + bb.w;
  const size_t idx = (size_t)rr * 1024 + c;
  *(float4*)&out[idx] = o;
  half4v hh;
  hh[0] = (_Float16)o.x; hh[1] = (_Float16)o.y;
  hh[2] = (_Float16)o.z; hh[3] = (_Float16)o.w;
  *(half4v*)&outh[idx] = hh;
}

// ---------------------------------------------------------------------------
extern "C" void kernel_launch(void* const* d_in, const int* in_sizes, int n_in,
                              void* d_out, int out_size, void* d_ws, size_t ws_size,
                              hipStream_t stream)
{
  const float* Q  = (const float*)d_in[0];
  const float* K  = (const float*)d_in[1];
  const float* V  = (const float*)d_in[2];
  const float* Wq = (const float*)d_in[3];
  const float* Wk = (const float*)d_in[4];
  const float* Wv = (const float*)d_in[5];
  const float* Wo = (const float*)d_in[6];
  const float* g1 = (const float*)d_in[7];
  const float* b1 = (const float*)d_in[8];
  const float* g2 = (const float*)d_in[9];
  const float* b2 = (const float*)d_in[10];
  float* out = (float*)d_out;

  char* base = (char*)d_ws;
  const size_t MB_ = 1024 * 1024;
  _Float16* Xq  = (_Float16*)(base +  0 * MB_);   // [0,8)
  _Float16* Xk  = (_Float16*)(base +  8 * MB_);   // [8,16)
  _Float16* Xv  = (_Float16*)(base + 16 * MB_);   // [16,24)
  _Float16* Wqh = (_Float16*)(base + 24 * MB_);   // [24,26)
  _Float16* Wkh = (_Float16*)(base + 26 * MB_);   // [26,28)
  _Float16* Wvh = (_Float16*)(base + 28 * MB_);   // [28,30)
  _Float16* Woh = (_Float16*)(base + 30 * MB_);   // [30,32)
  _Float16* Qh  = (_Float16*)(base + 32 * MB_);   // [32,40)
  _Float16* Kh  = (_Float16*)(base + 40 * MB_);   // [40,48)
  _Float16* Vh  = (_Float16*)(base + 48 * MB_);   // [48,56)
  _Float16* Vt  = (_Float16*)(base + 56 * MB_);   // [56,64)
  float*    O1  = (float*)(base + 64 * MB_);      // [64,80)
  int*      mQ  = (int*)(base + 80 * MB_);
  int*      mK  = mQ + NTOK;                      // peak: 80 MB + 32 KB (r8-proven)
  // post-attention aliases (source regions dead):
  float*    X1  = (float*)(base + 0 * MB_);       // over Xq∪Xk
  _Float16* X1h = (_Float16*)(base + 16 * MB_);   // over Xv
  float*    O2  = (float*)(base + 32 * MB_);      // over Qh∪Kh

  const dim3 bb(256);
  cvt_all<<<dim3(8208), bb, 0, stream>>>(Q, K, V, Wq, Wk, Wv, Wo,
                                         (const int*)d_in[11], (const int*)d_in[12],
                                         Xq, Xk, Xv, Wqh, Wkh, Wvh, Woh, mQ, mK);
  qkv_gemm<<<dim3(32, 8, 3), bb, 0, stream>>>(Xq, Xk, Xv, Wqh, Wkh, Wvh,
                                              mQ, mK, Qh, Kh, Vh);
  v_transpose<<<dim3(16, 64), bb, 0, stream>>>(Vh, Vt);
  attn_mfma3<<<dim3(16, 64), bb, 0, stream>>>(Qh, Kh, Vt, mQ, mK, O1);
  ln_f32h<<<dim3(4096), bb, 0, stream>>>(O1, g1, b1, mQ, X1, X1h);
  gemm_wo<<<dim3(32, 16), bb, 0, stream>>>(X1h, Woh, X1, O2);
  ln_f32<<<dim3(4096), bb, 0, stream>>>(O2, g2, b2, mQ, out);
}